// Round 2
// baseline (271.173 us; speedup 1.0000x reference)
//
#include <hip/hip_runtime.h>
#include <stdint.h>

typedef __attribute__((ext_vector_type(8))) short bf16x8;
typedef __attribute__((ext_vector_type(4))) float f32x4;

__device__ __forceinline__ float bf2f(unsigned short u) {
    union { unsigned int i; float f; } v; v.i = ((unsigned int)u) << 16; return v.f;
}
__device__ __forceinline__ unsigned short f2bf(float f) {
    union { float f; unsigned int i; } v; v.f = f;
    unsigned int b = v.i;
    b += 0x7FFFu + ((b >> 16) & 1u);   // round-to-nearest-even
    return (unsigned short)(b >> 16);
}

// ---------------- degree / CSR build ----------------

__global__ void count_kernel(const int* __restrict__ dst, int* __restrict__ counts, int E) {
    int e = blockIdx.x * blockDim.x + threadIdx.x;
    if (e < E) atomicAdd(&counts[dst[e]], 1);
}

__global__ void dinv_kernel(const int* __restrict__ counts, float* __restrict__ dinv, int N) {
    int n = blockIdx.x * blockDim.x + threadIdx.x;
    if (n < N) dinv[n] = rsqrtf((float)(counts[n] + 1));  // +1 self-loop; deg >= 1 always
}

// tile-local exclusive scan, tiles of 1024 (256 thr x 4 items)
__global__ void scan1(const int* __restrict__ counts, int* __restrict__ row_ptr,
                      int* __restrict__ partials, int N) {
    __shared__ int lds[256];
    int t = threadIdx.x;
    int base = blockIdx.x * 1024 + t * 4;
    int c[4];
#pragma unroll
    for (int i = 0; i < 4; ++i) c[i] = (base + i < N) ? counts[base + i] : 0;
    int s = c[0] + c[1] + c[2] + c[3];
    lds[t] = s;
    __syncthreads();
    for (int off = 1; off < 256; off <<= 1) {
        int v = (t >= off) ? lds[t - off] : 0;
        __syncthreads();
        lds[t] += v;
        __syncthreads();
    }
    int excl = lds[t] - s;
    int run = excl;
#pragma unroll
    for (int i = 0; i < 4; ++i) {
        if (base + i < N) row_ptr[base + i] = run;
        run += c[i];
    }
    if (t == 255) partials[blockIdx.x] = lds[255];
}

__global__ void scan2(int* partials, int NB) {
    if (threadIdx.x == 0 && blockIdx.x == 0) {
        int run = 0;
        for (int b = 0; b < NB; ++b) { int v = partials[b]; partials[b] = run; run += v; }
    }
}

__global__ void scan3(int* __restrict__ row_ptr, int* __restrict__ cursor,
                      const int* __restrict__ partials, int N, int E) {
    int n = blockIdx.x * blockDim.x + threadIdx.x;
    if (n < N) {
        int v = row_ptr[n] + partials[n >> 10];
        row_ptr[n] = v;
        cursor[n] = v;
    }
    if (n == 0) row_ptr[N] = E;
}

__global__ void scatter_kernel(const int* __restrict__ src, const int* __restrict__ dst,
                               int* __restrict__ cursor, int* __restrict__ csr, int E) {
    int e = blockIdx.x * blockDim.x + threadIdx.x;
    if (e < E) {
        int pos = atomicAdd(&cursor[dst[e]], 1);
        csr[pos] = src[e];
    }
}

// ---------------- GEMM: C_bf16[M,128] = A[M,128] @ W_f32[128,128], fp32 accum ----------------
// one wave computes a 16x128 row-stripe via 8 MFMA 16x16x32 tiles, K-loop of 4
// A_BF16: A is packed bf16 (ushort); else A is f32 (converted on the fly)

template <bool A_BF16>
__global__ __launch_bounds__(256) void gemm128(const void* __restrict__ Av,
                                               const float* __restrict__ W,
                                               unsigned short* __restrict__ C, int M) {
    // W transposed into LDS as bf16: Wt[n][k], +8 ushort pad -> 2-way bank aliasing (free)
    __shared__ __align__(16) unsigned short Wt[128][136];
    int t = threadIdx.x;
    for (int i = 0; i < 64; ++i) {
        int idx = t + i * 256;                   // idx = k*128 + n
        Wt[idx & 127][idx >> 7] = f2bf(W[idx]);
    }
    __syncthreads();

    int wave = t >> 6, lane = t & 63;
    int m0 = (blockIdx.x * 4 + wave) * 16;
    int mrow = lane & 15, quad = lane >> 4;

    f32x4 acc[8];
#pragma unroll
    for (int nt = 0; nt < 8; ++nt) acc[nt] = (f32x4){0.f, 0.f, 0.f, 0.f};

    int arow = m0 + mrow;
    bool valid = arow < M;
    int srow = valid ? arow : 0;

#pragma unroll
    for (int kb = 0; kb < 4; ++kb) {
        bf16x8 a;
        if (A_BF16) {
            const unsigned short* Arow = (const unsigned short*)Av + (size_t)srow * 128;
            a = *(const bf16x8*)(Arow + kb * 32 + quad * 8);
        } else {
            const float* Arow = (const float*)Av + (size_t)srow * 128;
            f32x4 lo = *(const f32x4*)(Arow + kb * 32 + quad * 8);
            f32x4 hi = *(const f32x4*)(Arow + kb * 32 + quad * 8 + 4);
#pragma unroll
            for (int i = 0; i < 4; ++i) { a[i] = (short)f2bf(lo[i]); a[i + 4] = (short)f2bf(hi[i]); }
        }
        if (!valid) a = (bf16x8){0, 0, 0, 0, 0, 0, 0, 0};
#pragma unroll
        for (int nt = 0; nt < 8; ++nt) {
            bf16x8 b = *(const bf16x8*)(&Wt[nt * 16 + mrow][kb * 32 + quad * 8]);
            acc[nt] = __builtin_amdgcn_mfma_f32_16x16x32_bf16(a, b, acc[nt], 0, 0, 0);
        }
    }

#pragma unroll
    for (int nt = 0; nt < 8; ++nt) {
#pragma unroll
        for (int r = 0; r < 4; ++r) {
            int row = m0 + quad * 4 + r;           // C/D: col=lane&15, row=quad*4+reg
            int col = nt * 16 + mrow;
            if (row < M) C[(size_t)row * 128 + col] = f2bf(acc[nt][r]);
        }
    }
}

// ---------------- aggregation: out[n] = relu(dinv[n] * sum_{s in nbr+self} dinv[s]*h[s] + b) ----------------
// h is bf16 [N,128]; one wave per node, lane owns cols {2*lane, 2*lane+1}
// OUT_BF16: write packed bf16 (feeds next GEMM); else write f32 (final output)

template <bool OUT_BF16>
__global__ __launch_bounds__(256) void agg_kernel(const unsigned short* __restrict__ h,
                                                  const int* __restrict__ row_ptr,
                                                  const int* __restrict__ csr,
                                                  const float* __restrict__ dinv,
                                                  const float* __restrict__ bias,
                                                  void* __restrict__ out, int N) {
    int n = blockIdx.x * 4 + (threadIdx.x >> 6);
    if (n >= N) return;
    int lane = threadIdx.x & 63;
    const unsigned int* h32 = (const unsigned int*)h;

    float di = dinv[n];
    unsigned int hv = h32[(size_t)n * 64 + lane];       // self-loop term
    float ax = di * bf2f((unsigned short)(hv & 0xFFFF));
    float ay = di * bf2f((unsigned short)(hv >> 16));

    int start = row_ptr[n], end = row_ptr[n + 1];
    for (int e0 = start; e0 < end; e0 += 64) {
        int cnt = min(64, end - e0);
        int s_l = 0; float w_l = 0.f;
        if (lane < cnt) { s_l = csr[e0 + lane]; w_l = dinv[s_l]; }
        for (int j = 0; j < cnt; ++j) {
            int   s = __shfl(s_l, j);
            float w = __shfl(w_l, j);
            unsigned int v = h32[(size_t)s * 64 + lane];
            ax += w * bf2f((unsigned short)(v & 0xFFFF));
            ay += w * bf2f((unsigned short)(v >> 16));
        }
    }

    float2 bv = ((const float2*)bias)[lane];
    float ox = fmaxf(ax * di + bv.x, 0.f);
    float oy = fmaxf(ay * di + bv.y, 0.f);
    if (OUT_BF16) {
        ((unsigned int*)out)[(size_t)n * 64 + lane] =
            (unsigned int)f2bf(ox) | ((unsigned int)f2bf(oy) << 16);
    } else {
        ((float2*)out)[(size_t)n * 64 + lane] = make_float2(ox, oy);
    }
}

// ---------------- launch ----------------

extern "C" void kernel_launch(void* const* d_in, const int* in_sizes, int n_in,
                              void* d_out, int out_size, void* d_ws, size_t ws_size,
                              hipStream_t stream) {
    const float* x  = (const float*)d_in[0];
    const int*   ei = (const int*)d_in[1];
    const float* W1 = (const float*)d_in[2];
    const float* b1 = (const float*)d_in[3];
    const float* W2 = (const float*)d_in[4];
    const float* b2 = (const float*)d_in[5];
    float* out = (float*)d_out;

    int N = in_sizes[0] / 128;
    int E = in_sizes[1] / 2;
    const int* src = ei;
    const int* dst = ei + E;

    char* p = (char*)d_ws;
    auto alloc = [&](size_t bytes) {
        char* r = p; p += (bytes + 255) & ~(size_t)255; return r;
    };
    int*   counts   = (int*)  alloc((size_t)N * 4);
    int*   row_ptr  = (int*)  alloc((size_t)(N + 1) * 4);
    int*   cursor   = (int*)  alloc((size_t)N * 4);
    float* dinv     = (float*)alloc((size_t)N * 4);
    int*   partials = (int*)  alloc(256 * 4);
    int*   csr      = (int*)  alloc((size_t)E * 4);
    unsigned short* h1   = (unsigned short*)alloc((size_t)N * 128 * 2);  // bf16
    unsigned short* out1 = (unsigned short*)alloc((size_t)N * 128 * 2);  // bf16

    hipMemsetAsync(counts, 0, (size_t)N * 4, stream);
    count_kernel<<<(E + 255) / 256, 256, 0, stream>>>(dst, counts, E);
    dinv_kernel<<<(N + 255) / 256, 256, 0, stream>>>(counts, dinv, N);
    int NB = (N + 1023) / 1024;
    scan1<<<NB, 256, 0, stream>>>(counts, row_ptr, partials, N);
    scan2<<<1, 64, 0, stream>>>(partials, NB);
    scan3<<<(N + 255) / 256, 256, 0, stream>>>(row_ptr, cursor, partials, N, E);
    scatter_kernel<<<(E + 255) / 256, 256, 0, stream>>>(src, dst, cursor, csr, E);

    int gblocks = (N + 63) / 64;
    gemm128<false><<<gblocks, 256, 0, stream>>>(x, W1, h1, N);
    agg_kernel<true><<<(N + 3) / 4, 256, 0, stream>>>(h1, row_ptr, csr, dinv, b1, out1, N);
    gemm128<true><<<gblocks, 256, 0, stream>>>(out1, W2, h1, N);
    agg_kernel<false><<<(N + 3) / 4, 256, 0, stream>>>(h1, row_ptr, csr, dinv, b2, out, N);
}

// Round 3
// 261.054 us; speedup vs baseline: 1.0388x; 1.0388x over previous
//
#include <hip/hip_runtime.h>
#include <stdint.h>

typedef __attribute__((ext_vector_type(8))) short bf16x8;
typedef __attribute__((ext_vector_type(4))) float f32x4;

__device__ __forceinline__ float bf2f(unsigned short u) {
    union { unsigned int i; float f; } v; v.i = ((unsigned int)u) << 16; return v.f;
}
__device__ __forceinline__ unsigned short f2bf(float f) {
    union { float f; unsigned int i; } v; v.f = f;
    unsigned int b = v.i;
    b += 0x7FFFu + ((b >> 16) & 1u);   // round-to-nearest-even
    return (unsigned short)(b >> 16);
}

// ---------------- degree / CSR build ----------------

__global__ void count_kernel(const int* __restrict__ dst, int* __restrict__ counts, int E) {
    int e = blockIdx.x * blockDim.x + threadIdx.x;
    if (e < E) atomicAdd(&counts[dst[e]], 1);
}

__global__ void dinv_kernel(const int* __restrict__ counts, float* __restrict__ dinv, int N) {
    int n = blockIdx.x * blockDim.x + threadIdx.x;
    if (n < N) dinv[n] = rsqrtf((float)(counts[n] + 1));  // +1 self-loop; deg >= 1 always
}

// tile-local exclusive scan, tiles of 1024 (256 thr x 4 items)
__global__ void scan1(const int* __restrict__ counts, int* __restrict__ row_ptr,
                      int* __restrict__ partials, int N) {
    __shared__ int lds[256];
    int t = threadIdx.x;
    int base = blockIdx.x * 1024 + t * 4;
    int c[4];
#pragma unroll
    for (int i = 0; i < 4; ++i) c[i] = (base + i < N) ? counts[base + i] : 0;
    int s = c[0] + c[1] + c[2] + c[3];
    lds[t] = s;
    __syncthreads();
    for (int off = 1; off < 256; off <<= 1) {
        int v = (t >= off) ? lds[t - off] : 0;
        __syncthreads();
        lds[t] += v;
        __syncthreads();
    }
    int excl = lds[t] - s;
    int run = excl;
#pragma unroll
    for (int i = 0; i < 4; ++i) {
        if (base + i < N) row_ptr[base + i] = run;
        run += c[i];
    }
    if (t == 255) partials[blockIdx.x] = lds[255];
}

__global__ void scan2(int* partials, int NB) {
    if (threadIdx.x == 0 && blockIdx.x == 0) {
        int run = 0;
        for (int b = 0; b < NB; ++b) { int v = partials[b]; partials[b] = run; run += v; }
    }
}

__global__ void scan3(int* __restrict__ row_ptr, int* __restrict__ cursor,
                      const int* __restrict__ partials, int N, int E) {
    int n = blockIdx.x * blockDim.x + threadIdx.x;
    if (n < N) {
        int v = row_ptr[n] + partials[n >> 10];
        row_ptr[n] = v;
        cursor[n] = v;
    }
    if (n == 0) row_ptr[N] = E;
}

__global__ void scatter_kernel(const int* __restrict__ src, const int* __restrict__ dst,
                               int* __restrict__ cursor, int* __restrict__ csr, int E) {
    int e = blockIdx.x * blockDim.x + threadIdx.x;
    if (e < E) {
        int pos = atomicAdd(&cursor[dst[e]], 1);
        csr[pos] = src[e];
    }
}

// ---------------- one-time conversions ----------------

// Wt[n][k] = bf16(W[k][n]) for both weight matrices (transposed for MFMA B-operand)
__global__ void conv_w(const float* __restrict__ W1, const float* __restrict__ W2,
                       unsigned short* __restrict__ Wt1, unsigned short* __restrict__ Wt2) {
    int t = blockIdx.x * 256 + threadIdx.x;       // 0..32767
    const float* W = (t < 16384) ? W1 : W2;
    unsigned short* O = (t < 16384) ? Wt1 : Wt2;
    int i = t & 16383;
    int n = i >> 7, k = i & 127;
    O[i] = f2bf(W[k * 128 + n]);
}

// x -> bf16, 4 elements/thread
__global__ void conv_x(const float* __restrict__ x, unsigned int* __restrict__ xb, int total4) {
    int t = blockIdx.x * 256 + threadIdx.x;
    if (t < total4) {
        f32x4 v = ((const f32x4*)x)[t];
        unsigned int lo = (unsigned int)f2bf(v[0]) | ((unsigned int)f2bf(v[1]) << 16);
        unsigned int hi = (unsigned int)f2bf(v[2]) | ((unsigned int)f2bf(v[3]) << 16);
        xb[t * 2] = lo;
        xb[t * 2 + 1] = hi;
    }
}

// ---------------- GEMM: C_bf16[M,128] = A_bf16[M,128] @ W (Wt pre-transposed bf16) ----------------
// one wave per 16 rows; B fragments straight from global (32 KB, L1-resident); no LDS

__global__ __launch_bounds__(256) void gemm128(const unsigned short* __restrict__ A,
                                               const unsigned short* __restrict__ Wt,
                                               unsigned short* __restrict__ C, int M) {
    int t = threadIdx.x;
    int wave = t >> 6, lane = t & 63;
    int m0 = (blockIdx.x * 4 + wave) * 16;
    int mrow = lane & 15, quad = lane >> 4;

    int arow = m0 + mrow;
    int srow = arow < M ? arow : M - 1;
    const unsigned short* Arow = A + (size_t)srow * 128;

    f32x4 acc[8];
#pragma unroll
    for (int nt = 0; nt < 8; ++nt) acc[nt] = (f32x4){0.f, 0.f, 0.f, 0.f};

#pragma unroll
    for (int kb = 0; kb < 4; ++kb) {
        bf16x8 a = *(const bf16x8*)(Arow + kb * 32 + quad * 8);
#pragma unroll
        for (int nt = 0; nt < 8; ++nt) {
            bf16x8 b = *(const bf16x8*)(Wt + (size_t)(nt * 16 + mrow) * 128 + kb * 32 + quad * 8);
            acc[nt] = __builtin_amdgcn_mfma_f32_16x16x32_bf16(a, b, acc[nt], 0, 0, 0);
        }
    }

#pragma unroll
    for (int nt = 0; nt < 8; ++nt) {
#pragma unroll
        for (int r = 0; r < 4; ++r) {
            int row = m0 + quad * 4 + r;           // C/D: col=lane&15, row=quad*4+reg
            if (row < M) C[(size_t)row * 128 + nt * 16 + mrow] = f2bf(acc[nt][r]);
        }
    }
}

// ---------------- aggregation: out[n] = relu(dinv[n] * sum_{s in nbr+self} dinv[s]*h[s] + b) ----------------
// h bf16 [N,128]; one wave per node, lane owns 2 cols; inner loop unrolled x4 for load overlap

template <bool OUT_BF16>
__global__ __launch_bounds__(256) void agg_kernel(const unsigned short* __restrict__ h,
                                                  const int* __restrict__ row_ptr,
                                                  const int* __restrict__ csr,
                                                  const float* __restrict__ dinv,
                                                  const float* __restrict__ bias,
                                                  void* __restrict__ out, int N) {
    int n = blockIdx.x * 4 + (threadIdx.x >> 6);
    if (n >= N) return;
    int lane = threadIdx.x & 63;
    const unsigned int* h32 = (const unsigned int*)h;

    float di = dinv[n];
    unsigned int hv = h32[(size_t)n * 64 + lane];       // self-loop term
    float ax0 = di * bf2f((unsigned short)(hv & 0xFFFF));
    float ay0 = di * bf2f((unsigned short)(hv >> 16));
    float ax1 = 0.f, ay1 = 0.f;

    int start = row_ptr[n], end = row_ptr[n + 1];
    for (int e0 = start; e0 < end; e0 += 64) {
        int cnt = min(64, end - e0);
        int s_l = 0; float w_l = 0.f;
        if (lane < cnt) { s_l = csr[e0 + lane]; w_l = dinv[s_l]; }
        int j = 0;
        for (; j + 4 <= cnt; j += 4) {
            int s0 = __shfl(s_l, j),     s1 = __shfl(s_l, j + 1);
            int s2 = __shfl(s_l, j + 2), s3 = __shfl(s_l, j + 3);
            float w0 = __shfl(w_l, j),     w1 = __shfl(w_l, j + 1);
            float w2 = __shfl(w_l, j + 2), w3 = __shfl(w_l, j + 3);
            unsigned int v0 = h32[(size_t)s0 * 64 + lane];
            unsigned int v1 = h32[(size_t)s1 * 64 + lane];
            unsigned int v2 = h32[(size_t)s2 * 64 + lane];
            unsigned int v3 = h32[(size_t)s3 * 64 + lane];
            ax0 += w0 * bf2f((unsigned short)(v0 & 0xFFFF));
            ay0 += w0 * bf2f((unsigned short)(v0 >> 16));
            ax1 += w1 * bf2f((unsigned short)(v1 & 0xFFFF));
            ay1 += w1 * bf2f((unsigned short)(v1 >> 16));
            ax0 += w2 * bf2f((unsigned short)(v2 & 0xFFFF));
            ay0 += w2 * bf2f((unsigned short)(v2 >> 16));
            ax1 += w3 * bf2f((unsigned short)(v3 & 0xFFFF));
            ay1 += w3 * bf2f((unsigned short)(v3 >> 16));
        }
        for (; j < cnt; ++j) {
            int   s = __shfl(s_l, j);
            float w = __shfl(w_l, j);
            unsigned int v = h32[(size_t)s * 64 + lane];
            ax0 += w * bf2f((unsigned short)(v & 0xFFFF));
            ay0 += w * bf2f((unsigned short)(v >> 16));
        }
    }

    float2 bv = ((const float2*)bias)[lane];
    float ox = fmaxf((ax0 + ax1) * di + bv.x, 0.f);
    float oy = fmaxf((ay0 + ay1) * di + bv.y, 0.f);
    if (OUT_BF16) {
        ((unsigned int*)out)[(size_t)n * 64 + lane] =
            (unsigned int)f2bf(ox) | ((unsigned int)f2bf(oy) << 16);
    } else {
        ((float2*)out)[(size_t)n * 64 + lane] = make_float2(ox, oy);
    }
}

// ---------------- launch ----------------

extern "C" void kernel_launch(void* const* d_in, const int* in_sizes, int n_in,
                              void* d_out, int out_size, void* d_ws, size_t ws_size,
                              hipStream_t stream) {
    const float* x  = (const float*)d_in[0];
    const int*   ei = (const int*)d_in[1];
    const float* W1 = (const float*)d_in[2];
    const float* b1 = (const float*)d_in[3];
    const float* W2 = (const float*)d_in[4];
    const float* b2 = (const float*)d_in[5];
    float* out = (float*)d_out;

    int N = in_sizes[0] / 128;
    int E = in_sizes[1] / 2;
    const int* src = ei;
    const int* dst = ei + E;

    char* p = (char*)d_ws;
    auto alloc = [&](size_t bytes) {
        char* r = p; p += (bytes + 255) & ~(size_t)255; return r;
    };
    int*   counts   = (int*)  alloc((size_t)N * 4);
    int*   row_ptr  = (int*)  alloc((size_t)(N + 1) * 4);
    int*   cursor   = (int*)  alloc((size_t)N * 4);
    float* dinv     = (float*)alloc((size_t)N * 4);
    int*   partials = (int*)  alloc(256 * 4);
    int*   csr      = (int*)  alloc((size_t)E * 4);
    unsigned short* xb   = (unsigned short*)alloc((size_t)N * 128 * 2);  // bf16 x
    unsigned short* h1   = (unsigned short*)alloc((size_t)N * 128 * 2);  // bf16
    unsigned short* out1 = (unsigned short*)alloc((size_t)N * 128 * 2);  // bf16
    unsigned short* Wt1  = (unsigned short*)alloc(16384 * 2);            // bf16 W1^T
    unsigned short* Wt2  = (unsigned short*)alloc(16384 * 2);            // bf16 W2^T

    hipMemsetAsync(counts, 0, (size_t)N * 4, stream);
    count_kernel<<<(E + 255) / 256, 256, 0, stream>>>(dst, counts, E);
    dinv_kernel<<<(N + 255) / 256, 256, 0, stream>>>(counts, dinv, N);
    int NB = (N + 1023) / 1024;
    scan1<<<NB, 256, 0, stream>>>(counts, row_ptr, partials, N);
    scan2<<<1, 64, 0, stream>>>(partials, NB);
    scan3<<<(N + 255) / 256, 256, 0, stream>>>(row_ptr, cursor, partials, N, E);
    scatter_kernel<<<(E + 255) / 256, 256, 0, stream>>>(src, dst, cursor, csr, E);

    conv_w<<<128, 256, 0, stream>>>(W1, W2, Wt1, Wt2);
    int total4 = N * 128 / 4;
    conv_x<<<(total4 + 255) / 256, 256, 0, stream>>>(x, (unsigned int*)xb, total4);

    int gblocks = (N + 63) / 64;
    gemm128<<<gblocks, 256, 0, stream>>>(xb, Wt1, h1, N);
    agg_kernel<true><<<(N + 3) / 4, 256, 0, stream>>>(h1, row_ptr, csr, dinv, b1, out1, N);
    gemm128<<<gblocks, 256, 0, stream>>>(out1, Wt2, h1, N);
    agg_kernel<false><<<(N + 3) / 4, 256, 0, stream>>>(h1, row_ptr, csr, dinv, b2, out, N);
}